// Round 6
// baseline (1568.290 us; speedup 1.0000x reference)
//
#include <hip/hip_runtime.h>
#include <hip/hip_bf16.h>
#include <cstdint>

// Set2Set forward, 3 steps. N=200000, B=1024 segments, D=256. All f32 I/O.
// Round 12: single cooperative kernel, 1024 blocks x 256 threads, 4
// blocks/CU co-resident (launch_bounds(256,4), 38.4KB LDS). Fixes r8's
// fused-version mistakes: full 1024-block attn parallelism (1 segment per
// block, r11's proven two-pass LDS-tile loop with named-register staging),
// GEMM re-tiled to 32x32/block (4 blocks/CU vs the 7-dispatch version's
// 1/CU) with the SAME per-element accumulation order (bitwise-identical
// gates). 6 agent-scope grid barriers replace 6 launch boundaries.
// c and LSTM bias live in registers.

#define NN     200000
#define BSEG   1024
#define DD     256
#define KA     512     // collapsed K
#define FOURD  1024
#define NBLK   1024

using bf16x8 = __attribute__((ext_vector_type(8))) __bf16;
using f32x4  = __attribute__((ext_vector_type(4))) float;

__device__ __forceinline__ float bf2f(unsigned int u) {
  union { unsigned int i; float f; } v; v.i = (u & 0xffffu) << 16; return v.f;
}
__device__ __forceinline__ unsigned short f2bf(float f) {
  union { float f; unsigned int i; } v; v.f = f;
  unsigned int x = v.i;
  if ((x & 0x7fffffffu) > 0x7f800000u) return (unsigned short)((x >> 16) | 0x40);
  return (unsigned short)((x + 0x7fffu + ((x >> 16) & 1u)) >> 16);
}
__device__ __forceinline__ void split_bf(float f, unsigned short& hi, unsigned short& lo) {
  hi = f2bf(f);
  lo = f2bf(f - bf2f(hi));
}

// Generation grid barrier (r8-proven). bar[0]=arrive count, bar[1]=generation.
// All NBLK blocks co-resident: launch_bounds(256,4) caps VGPR at 128 and
// LDS is 38.4KB <= 40KB -> 4 blocks/CU x 256 CU = 1024.
__device__ __forceinline__ void grid_barrier(int* bar, int& gen) {
  __syncthreads();
  if (threadIdx.x == 0) {
    __threadfence();                 // device-scope release of phase writes
    gen++;
    int prev = __hip_atomic_fetch_add(&bar[0], 1, __ATOMIC_ACQ_REL,
                                      __HIP_MEMORY_SCOPE_AGENT);
    if (prev == NBLK - 1) {
      __hip_atomic_store(&bar[0], 0, __ATOMIC_RELAXED, __HIP_MEMORY_SCOPE_AGENT);
      __hip_atomic_fetch_add(&bar[1], 1, __ATOMIC_RELEASE,
                             __HIP_MEMORY_SCOPE_AGENT);
    } else {
      while (__hip_atomic_load(&bar[1], __ATOMIC_ACQUIRE,
                               __HIP_MEMORY_SCOPE_AGENT) < gen)
        __builtin_amdgcn_s_sleep(2);
    }
  }
  __syncthreads();
}

// ---- attn staging: NAMED registers st0..st7, literal-index macros --------
#define LD1(dst, kk, base, RR) do {                                         \
    int i_ = w + 4 * (kk);                                                  \
    int ic_ = i_ < (RR) ? i_ : (RR) - 1;                                    \
    if (ic_ < 0) ic_ = 0;                                                   \
    int row_ = (base) + ic_;                                                \
    if (row_ > NN - 1) row_ = NN - 1;                                       \
    dst = *(const float4*)(x + (size_t)row_ * DD + lane * 4);               \
  } while (0)

#define ST1(src, kk) do {                                                   \
    int i_ = w + 4 * (kk);                                                  \
    if (i_ < R) *(float4*)&xt[i_ * DD + ((4 * lane) ^ (4 * (i_ & 7)))] = src; \
  } while (0)

#define LDALL(base, RR) do {                                                \
    LD1(st0, 0, base, RR); LD1(st1, 1, base, RR);                           \
    LD1(st2, 2, base, RR); LD1(st3, 3, base, RR);                           \
    LD1(st4, 4, base, RR); LD1(st5, 5, base, RR);                           \
    LD1(st6, 6, base, RR); LD1(st7, 7, base, RR);                           \
  } while (0)

#define STALL() do {                                                        \
    ST1(st0, 0); ST1(st1, 1); ST1(st2, 2); ST1(st3, 3);                     \
    ST1(st4, 4); ST1(st5, 5); ST1(st6, 6); ST1(st7, 7);                     \
  } while (0)

__global__ __launch_bounds__(256, 4) void set2set_all(
    const float* __restrict__ x, const int* __restrict__ batch,
    const float* __restrict__ qst, const float* __restrict__ Wih,
    const float* __restrict__ Whh, const float* __restrict__ bih,
    const float* __restrict__ bhh,
    int* __restrict__ segs,
    unsigned short* __restrict__ W1hi, unsigned short* __restrict__ W1lo,
    unsigned short* __restrict__ W2hi, unsigned short* __restrict__ W2lo,
    unsigned short* __restrict__ Ahi, unsigned short* __restrict__ Alo,
    float* __restrict__ gates, int* __restrict__ bar,
    float* __restrict__ qout) {
  int b = blockIdx.x, t = threadIdx.x;
  int w = t >> 6, lane = t & 63;
  int r16 = lane & 15, quad = lane >> 4;
  int gen = 0;

  // ---------------- prep (bitwise-identical to prep_all) ----------------
  #pragma unroll
  for (int rep = 0; rep < 2; ++rep) {
    int idx = b * 256 + t + rep * 262144;    // covers 524288
    int j = idx >> 9, kk = idx & 511;
    float w1 = Wih[idx];
    float w2 = (kk < 256) ? w1 + Whh[j * 256 + kk] : w1;
    unsigned short hi, lo;
    split_bf(w1, hi, lo); W1hi[idx] = hi; W1lo[idx] = lo;
    split_bf(w2, hi, lo); W2hi[idx] = hi; W2lo[idx] = lo;
    float a = qst[idx];
    split_bf(a, hi, lo); Ahi[idx] = hi; Alo[idx] = lo;
  }
  {
    int gidx = b * 256 + t;
    if (gidx <= BSEG) {
      int lo = 0, hi = NN;
      while (lo < hi) { int mid = (lo + hi) >> 1; if (batch[mid] < gidx) lo = mid + 1; else hi = mid; }
      segs[gidx] = lo;
    }
  }
  // LSTM bias for channel t, all 4 gates — registers, constant across steps.
  float bi0 = bih[t]       + bhh[t];
  float bi1 = bih[256 + t] + bhh[256 + t];
  float bi2 = bih[512 + t] + bhh[512 + t];
  float bi3 = bih[768 + t] + bhh[768 + t];

  grid_barrier(bar, gen);

  int s0 = segs[b], e0 = segs[b + 1];

  // GEMM geometry: block b owns 32x32 tile (m0, n0); wave w owns the
  // (w>>1, w&1) 16x16 quadrant, full K=512.
  int m0 = (b >> 5) << 5;
  int n0 = (b & 31) << 5;
  int arow = m0 + ((w >> 1) << 4) + r16;
  int bcol = n0 + ((w & 1) << 4) + r16;

  __shared__ float shq[DD];                 // q, XOR-swizzled
  __shared__ __align__(16) float xt[32 * DD];
  __shared__ float se[32];
  __shared__ float smw[4], slw[4];
  __shared__ __align__(16) float sv[4][DD];

  float cc = 0.f;                           // LSTM cell state, register

  for (int step = 0; step < 3; ++step) {
    const unsigned short* Whi_ = step ? W2hi : W1hi;
    const unsigned short* Wlo_ = step ? W2lo : W1lo;

    // ---------------- GEMM: gates = (Ahi+Alo) @ (Whi+Wlo)^T ---------------
    // K-chunk order kk*32 + quad*8 (kk=0..15) and mfma triple (a*bh, a*bl,
    // al*bh) match the 7-dispatch gemm exactly -> bitwise-identical gates.
    {
      const unsigned short* ah  = Ahi  + (size_t)arow * KA + quad * 8;
      const unsigned short* al  = Alo  + (size_t)arow * KA + quad * 8;
      const unsigned short* bhp = Whi_ + (size_t)bcol * KA + quad * 8;
      const unsigned short* blp = Wlo_ + (size_t)bcol * KA + quad * 8;
      f32x4 acc = {};
      #pragma unroll 4
      for (int kk = 0; kk < 16; ++kk) {
        bf16x8 a  = *(const bf16x8*)(ah  + kk * 32);
        bf16x8 aL = *(const bf16x8*)(al  + kk * 32);
        bf16x8 bh = *(const bf16x8*)(bhp + kk * 32);
        bf16x8 bl = *(const bf16x8*)(blp + kk * 32);
        acc = __builtin_amdgcn_mfma_f32_16x16x32_bf16(a,  bh, acc, 0, 0, 0);
        acc = __builtin_amdgcn_mfma_f32_16x16x32_bf16(a,  bl, acc, 0, 0, 0);
        acc = __builtin_amdgcn_mfma_f32_16x16x32_bf16(aL, bh, acc, 0, 0, 0);
      }
      int orow = m0 + ((w >> 1) << 4) + quad * 4;
      int ocol = n0 + ((w & 1) << 4) + r16;
      #pragma unroll
      for (int r = 0; r < 4; ++r)
        gates[(size_t)(orow + r) * FOURD + ocol] = acc[r];
    }
    grid_barrier(bar, gen);                  // gates complete

    // ---------------- LSTM pointwise + attn, segment b --------------------
    const float* g = gates + (size_t)b * FOURD;
    float gi = g[t]       + bi0;
    float gf = g[256 + t] + bi1;
    float gg = g[512 + t] + bi2;
    float go = g[768 + t] + bi3;
    float ig = 1.f / (1.f + expf(-gi));
    float fg = 1.f / (1.f + expf(-gf));
    float gt = tanhf(gg);
    float og = 1.f / (1.f + expf(-go));
    float cn = fg * cc + ig * gt;
    cc = cn;
    float hn = og * tanhf(cn);

    shq[t ^ (4 * ((t >> 5) & 7))] = hn;     // involution on bits 2-4
    {
      unsigned short hi, lo; split_bf(hn, hi, lo);
      size_t ro = (size_t)b * KA;
      Ahi[ro + t] = hi;  Alo[ro + t] = lo;  // h-part [0,256)
      qout[(size_t)b * 512 + t] = hn;       // output q half
    }
    __syncthreads();

    int s = s0, e = e0;
    int r8 = lane >> 3, d8 = lane & 7;

    float m = -3.402823466e38f, l = 0.f;
    float4 v = {0.f, 0.f, 0.f, 0.f};

    int R = e - s; if (R > 32) R = 32;      // <=0 if empty segment
    float4 st0, st1, st2, st3, st4, st5, st6, st7;
    LDALL(s, R);                            // prologue: tile 0 into regs

    for (int tb = s; tb < e; tb += 32) {
      __syncthreads();                      // xt/se free (prev tile consumed)
      STALL();                              // swizzled reg->LDS
      __syncthreads();                      // xt ready

      int base2 = tb + 32;
      int Rn = e - base2; if (Rn > 32) Rn = 32;
      LDALL(base2, Rn);                     // T14: next tile in flight

      // pass E: row i = 8w + r8, lane-chunk d8 covers words [32*d8, +32)
      {
        int i = 8 * w + r8;
        int key = 4 * (i & 7);              // == 4*r8
        float4 acc = {0.f, 0.f, 0.f, 0.f};
        #pragma unroll
        for (int ccn = 0; ccn < 8; ++ccn) {
          int jj = d8 * 32 + 4 * ccn;
          float4 xv = *(const float4*)&xt[i * DD + (jj ^ key)];
          float4 qv = *(const float4*)&shq[jj ^ (4 * d8)];   // broadcast
          acc.x += xv.x * qv.x; acc.y += xv.y * qv.y;
          acc.z += xv.z * qv.z; acc.w += xv.w * qv.w;
        }
        float ee = (acc.x + acc.y) + (acc.z + acc.w);
        ee += __shfl_xor(ee, 1);
        ee += __shfl_xor(ee, 2);
        ee += __shfl_xor(ee, 4);
        if (i >= R) ee = -3.402823466e38f;  // mask garbage rows
        if (d8 == 0) se[i] = ee;
      }
      __syncthreads();                      // se ready

      // tile max -> block-uniform online max
      float tm = se[lane & 31];
      #pragma unroll
      for (int mask = 16; mask; mask >>= 1) tm = fmaxf(tm, __shfl_xor(tm, mask));
      float mn = fmaxf(m, tm);
      float alpha = __expf(m - mn);
      l *= alpha; v.x *= alpha; v.y *= alpha; v.z *= alpha; v.w *= alpha;

      // pass V: wave w sweeps rows {w, w+4, ..., w+28}
      #pragma unroll
      for (int k = 0; k < 8; ++k) {
        int i = w + 4 * k;
        if (i < R) {
          float wv = __expf(se[i] - mn);    // broadcast
          float4 xv = *(const float4*)&xt[i * DD + ((4 * lane) ^ (4 * (i & 7)))];
          l += wv;
          v.x += wv * xv.x; v.y += wv * xv.y; v.z += wv * xv.z; v.w += wv * xv.w;
        }
      }
      m = mn;
      R = Rn;
    }

    // merge 4 wave-partials
    if (lane == 0) { smw[w] = m; slw[w] = l; }
    *(float4*)(&sv[w][lane * 4]) = v;
    __syncthreads();

    float M = fmaxf(fmaxf(smw[0], smw[1]), fmaxf(smw[2], smw[3]));
    if (M < -1e37f) M = 0.f;                // mirror reference isfinite guard
    float a0 = __expf(smw[0] - M), a1 = __expf(smw[1] - M);
    float a2 = __expf(smw[2] - M), a3 = __expf(smw[3] - M);
    float L = slw[0] * a0 + slw[1] * a1 + slw[2] * a2 + slw[3] * a3;
    float r = (sv[0][t] * a0 + sv[1][t] * a1 + sv[2][t] * a2 + sv[3][t] * a3)
              / (L + 1e-16f);

    unsigned short hi, lo; split_bf(r, hi, lo);
    size_t ro = (size_t)b * KA;
    Ahi[ro + DD + t] = hi;  Alo[ro + DD + t] = lo; // r-part [256,512)
    qout[(size_t)b * 512 + DD + t] = r;            // output r half

    if (step < 2) grid_barrier(bar, gen);   // A ready for next GEMM
  }
}

// ---- launch --------------------------------------------------------------
extern "C" void kernel_launch(void* const* d_in, const int* in_sizes, int n_in,
                              void* d_out, int out_size, void* d_ws, size_t ws_size,
                              hipStream_t stream) {
  const float* x    = (const float*)d_in[0];
  const int*   batc = (const int*)d_in[2];
  const float* qst  = (const float*)d_in[3];
  const float* Wih  = (const float*)d_in[4];
  const float* Whh  = (const float*)d_in[5];
  const float* bih  = (const float*)d_in[6];
  const float* bhh  = (const float*)d_in[7];
  float* out = (float*)d_out;

  char* ws = (char*)d_ws;
  size_t off = 0;
  auto alloc = [&](size_t bytes) -> void* {
    void* p = ws + off; off = (off + bytes + 255) & ~(size_t)255; return p;
  };
  int*            bar  = (int*)alloc(256);
  int*            segs = (int*)alloc((size_t)(BSEG + 1) * 4);
  unsigned short* W1hi = (unsigned short*)alloc((size_t)FOURD * KA * 2);
  unsigned short* W1lo = (unsigned short*)alloc((size_t)FOURD * KA * 2);
  unsigned short* W2hi = (unsigned short*)alloc((size_t)FOURD * KA * 2);
  unsigned short* W2lo = (unsigned short*)alloc((size_t)FOURD * KA * 2);
  unsigned short* Ahi  = (unsigned short*)alloc((size_t)BSEG * KA * 2);
  unsigned short* Alo  = (unsigned short*)alloc((size_t)BSEG * KA * 2);
  float*          gate = (float*)alloc((size_t)BSEG * FOURD * 4);

  hipMemsetAsync(bar, 0, 2 * sizeof(int), stream);
  set2set_all<<<NBLK, 256, 0, stream>>>(
      x, batc, qst, Wih, Whh, bih, bhh,
      segs, W1hi, W1lo, W2hi, W2lo, Ahi, Alo, gate, bar, out);
}